// Round 2
// baseline (184.565 us; speedup 1.0000x reference)
//
#include <hip/hip_runtime.h>
#include <hip/hip_fp16.h>

#define N_NODES 10000
#define BATCH   8
#define IN_SZ   64
#define UNITS   64
#define ROW_U   256            // uints per f16 row (512 f16 = 4 stripes of 64)
#define RCAP    96             // fixed per-row edge capacity (P(deg>96) ~ 1e-18)
#define STR     (N_NODES * 64) // uints per stripe (640,000)

typedef unsigned int uint;
typedef unsigned short ushort;
typedef __attribute__((ext_vector_type(8))) _Float16 half8;
typedef __attribute__((ext_vector_type(4))) float float4v;
typedef __attribute__((ext_vector_type(2))) uint uint2v;

// ---- numeric helpers -------------------------------------------------------
// Edge values bf16-packed (high 16 bits ARE the fp32 bits -> SALU decode).
__device__ inline uint f2bf_bits(float f) {
    uint u = __float_as_uint(f);
    uint r = ((u >> 16) & 1u) + 0x7FFFu;
    return (u + r) >> 16;
}
// x tensors stored as packed fp16 (RNE): enables v_fma_mix_f32 in spmm loop.
__device__ inline uint pack2h(float a, float b) {
    return (uint)__half_as_ushort(__float2half(a)) |
           ((uint)__half_as_ushort(__float2half(b)) << 16);
}
__device__ inline float h_lo(uint u) {
    return __half2float(__ushort_as_half((ushort)(u & 0xFFFFu)));
}
__device__ inline float h_hi(uint u) {
    return __half2float(__ushort_as_half((ushort)(u >> 16)));
}

// ---------------------------------------------------------------------------
// k_transpose_scatter: transpose in[b,n,i] fp32 -> x0 stripe layout fp16.
// This round: float4 (16B) input loads, dwordx2 (8B) packed stores ->
// 1.28M threads (was 2.56M), same bytes, half the waves/issues.
// Edge scatter (first nnz threads) unchanged: packed 4-byte records,
// low 14 bits = col, high 16 bits = val as bf16.
// ---------------------------------------------------------------------------
__global__ __launch_bounds__(256) void k_transpose_scatter(
    const float4v* __restrict__ in4, uint* __restrict__ x0,
    const int* __restrict__ rows, const int* __restrict__ cols,
    const float* __restrict__ vals, int* __restrict__ cursor,
    uint* __restrict__ edges, int nnz) {
    int gid = blockIdx.x * 256 + threadIdx.x;      // 1,280,000 total
    if (gid < nnz) {
        int r   = rows[gid];
        int pos = r * RCAP + atomicAdd(&cursor[r], 1);
        edges[pos] = (uint)cols[gid] | (f2bf_bits(vals[gid]) << 16);
    }
    int i4 = gid & 15;          // 4-channel chunk (channels 4*i4 .. 4*i4+3)
    int b  = (gid >> 4) & 7;    // batch
    int n  = gid >> 7;          // node
    float4v v = __builtin_nontemporal_load(
        &in4[((size_t)b * N_NODES + n) * 16 + i4]);
    int c_u = b * 32 + i4 * 2;  // uint index within 256-uint row
    int q   = c_u >> 6;         // stripe (= b>>1, constant per thread)
    uint2v pk;
    pk.x = pack2h(v.x, v.y);
    pk.y = pack2h(v.z, v.w);
    __builtin_nontemporal_store(pk,
        (uint2v*)(x0 + (size_t)q * STR + (size_t)n * 64 + (c_u & 63)));
}

// ---------------------------------------------------------------------------
// k_spmm: one WAVE per (row, stripe); lane owns one uint (2 fp16 cols).
// Evidence trail: r13 VALU fixes -> SALU addressing; r14 fp16/fma_mix halved
// inner VALU but was ~neutral => NOT VALU-bound. Theory: per-wave serialized
// latency (s_load edges -> gather -> fma per 8-edge block, no overlap across
// the backedge). Fix: explicit 2-deep software pipeline -- next block's
// s_load + gathers issue BEFORE current block's FMAs. Unified validity
// masking (SALU cselect) merges main loop + tail into one pipelined path.
// XCD pinning kept: stripe q only on XCDs {2q,2q+1} (2.56MB < 4MB L2).
// ---------------------------------------------------------------------------
#define LOADE(EP, OFF)                                                        \
    _Pragma("unroll") for (int j = 0; j < 8; ++j) EP[j] = edges[(OFF) + j];

#define GATHERX(XR, EP)                                                       \
    _Pragma("unroll") for (int j = 0; j < 8; ++j) {                           \
        uint c = EP[j] & 0x3FFFu;                                             \
        if (c > N_NODES - 1) c = N_NODES - 1; /* s_min (poisoned slots) */    \
        XR[j] = xq[c * 64u + lane];           /* SALU idx + saddr gather */   \
    }

#define FMA8(EP, XR, G0)                                                      \
    _Pragma("unroll") for (int j = 0; j < 8; ++j) {                           \
        uint vb = ((G0) + j < cnt) ? (EP[j] & 0xFFFF0000u) : 0u; /* SALU */   \
        float vj = __uint_as_float(vb);                                       \
        a0 += vj * h_lo(XR[j]); /* v_fma_mix_f32 */                           \
        a1 += vj * h_hi(XR[j]); /* v_fma_mix_f32 */                           \
    }

__global__ __launch_bounds__(256) void k_spmm(const int* __restrict__ cursor,
                                              const uint* __restrict__ edges,
                                              const uint* __restrict__ xin,
                                              uint* __restrict__ xout,
                                              const uint* __restrict__ xsub,
                                              float scale) {
    int L    = blockIdx.x;              // 10000 blocks
    int q    = (L & 7) >> 1;            // stripe pinned to XCD pair {2q,2q+1}
    int rb   = ((L >> 3) << 1) | (L & 1);   // 0..2499, bijective per stripe
    int wave = threadIdx.x >> 6;
    uint lane = threadIdx.x & 63;
    int row  = rb * 4 + wave;

    const uint* xq = xin + (size_t)q * STR;
    int base = row * RCAP;
    int cnt  = __builtin_amdgcn_readfirstlane(cursor[row]);
    int nblk = (cnt + 7) >> 3;          // >= 1 (diagonal guarantees cnt >= 1)

    // hoist the subtract-operand load: latency hides under the edge loop
    uint sx = 0;
    if (xsub) sx = __builtin_nontemporal_load(
        &xsub[(size_t)q * STR + (size_t)row * 64 + lane]);

    float a0 = 0.f, a1 = 0.f;

    uint epA[8], epB[8];
    uint xA[8], xB[8];

    // prologue: block 0 in flight
    LOADE(epA, base);
    GATHERX(xA, epA);

    int k = 0;
    for (; k + 2 <= nblk; k += 2) {
        LOADE(epB, base + 8 * (k + 1));   // stage k+1: s_load
        GATHERX(xB, epB);                 //            gathers in flight
        FMA8(epA, xA, 8 * k);             // consume stage k
        if (k + 2 < nblk) {               // refill A with stage k+2
            LOADE(epA, base + 8 * (k + 2));
            GATHERX(xA, epA);
        }
        FMA8(epB, xB, 8 * (k + 1));       // consume stage k+1
    }
    if (k < nblk) FMA8(epA, xA, 8 * k);   // odd block count: last stage in A

    float o0 = scale * a0, o1 = scale * a1;
    if (xsub) {
        o0 -= h_lo(sx);
        o1 -= h_hi(sx);
    }
    __builtin_nontemporal_store(pack2h(o0, o1),
        &xout[(size_t)q * STR + (size_t)row * 64 + lane]);
}

// ---------------------------------------------------------------------------
// k_combine (MFMA f16): out[b,n,u] = bias[u] + sum_k A[(b,n), k] * Wp[k, u].
// This round: af[] global gathers issue BEFORE the LDS weight fill +
// __syncthreads, so their ~400cy latency hides under the staging phase.
// 1-D grid 157*8; b = L&7 pins batch b (stripe b>>1) to XCD pair {2q,2q+1},
// matching spmm write locality.
// ---------------------------------------------------------------------------
__global__ __launch_bounds__(256) void k_combine(const uint* __restrict__ x0,
                                                 const uint* __restrict__ x1,
                                                 const uint* __restrict__ x2,
                                                 const float* __restrict__ W,
                                                 const float* __restrict__ bias,
                                                 float* __restrict__ out) {
    __shared__ ushort sWt[64][200];    // [u][k] f16, pad 192->200 (25.6 KB)
    int t    = threadIdx.x;
    int wave = t >> 6, lane = t & 63;
    int mrow = lane & 15, quad = lane >> 4;
    int L    = blockIdx.x;
    int b    = L & 7;                  // XCD-pinned batch -> stripe b>>1
    int n0   = (L >> 3) * 64 + wave * 16;

    const uint* xs[3] = {x0, x1, x2};
    int an = n0 + mrow;
    if (an > N_NODES - 1) an = N_NODES - 1;    // clamp tail reads

    // issue the x gathers FIRST (independent of LDS) -- overlap with W stage
    half8 af[6];
#pragma unroll
    for (int kb = 0; kb < 6; ++kb) {
        int mat = kb >> 1;
        int c_u = b * 32 + (kb & 1) * 16 + quad * 4;      // column uint index
        int q   = c_u >> 6;                               // = b>>1
        af[kb] = __builtin_nontemporal_load(
            (const half8*)(xs[mat] + (size_t)q * STR + (size_t)an * 64 +
                           (c_u & 63)));
    }

    for (int e = t; e < 192 * 64; e += 256) {
        int f = e >> 6;                // fan_in row = i*3 + m
        int u = e & 63;
        int i = f / 3;
        int m = f - 3 * i;
        sWt[u][m * 64 + i] = __half_as_ushort(__float2half(W[e]));
    }
    __syncthreads();

    float4v acc[4];
#pragma unroll
    for (int ut = 0; ut < 4; ++ut) acc[ut] = (float4v){0.f, 0.f, 0.f, 0.f};

#pragma unroll
    for (int kb = 0; kb < 6; ++kb)
#pragma unroll
        for (int ut = 0; ut < 4; ++ut)
            acc[ut] = __builtin_amdgcn_mfma_f32_16x16x32_f16(
                af[kb],
                *(const half8*)&sWt[ut * 16 + mrow][kb * 32 + quad * 8],
                acc[ut], 0, 0, 0);

#pragma unroll
    for (int ut = 0; ut < 4; ++ut) {
        float bv = bias[ut * 16 + mrow];
        int u = ut * 16 + mrow;
#pragma unroll
        for (int r = 0; r < 4; ++r) {
            int n = n0 + quad * 4 + r;
            if (n < N_NODES)
                __builtin_nontemporal_store(acc[ut][r] + bv,
                    &out[((size_t)b * N_NODES + n) * UNITS + u]);
        }
    }
}

// ---------------------------------------------------------------------------
extern "C" void kernel_launch(void* const* d_in, const int* in_sizes, int n_in,
                              void* d_out, int out_size, void* d_ws, size_t ws_size,
                              hipStream_t stream) {
    const float* inputs = (const float*)d_in[0];
    const int*   rows   = (const int*)d_in[1];
    const int*   cols   = (const int*)d_in[2];
    const float* vals   = (const float*)d_in[3];
    const float* W      = (const float*)d_in[4];
    const float* bias   = (const float*)d_in[5];
    float*       out    = (float*)d_out;
    int nnz = in_sizes[1];

    char* p = (char*)d_ws;
    auto alloc = [&](size_t bytes) {
        char* r = p;
        p += (bytes + 255) & ~(size_t)255;
        return r;
    };
    uint* x0     = (uint*)alloc(sizeof(uint) * (size_t)N_NODES * ROW_U);
    uint* x1     = (uint*)alloc(sizeof(uint) * (size_t)N_NODES * ROW_U);
    uint* x2     = (uint*)alloc(sizeof(uint) * (size_t)N_NODES * ROW_U);
    int*  cursor = (int*)alloc(sizeof(int) * N_NODES);
    uint* edges  = (uint*)alloc(sizeof(uint) * (size_t)N_NODES * RCAP);

    (void)hipMemsetAsync(cursor, 0, sizeof(int) * N_NODES, stream);
    k_transpose_scatter<<<N_NODES / 2, 256, 0, stream>>>(
        (const float4v*)inputs, x0, rows, cols, vals, cursor, edges, nnz);
    k_spmm<<<N_NODES, 256, 0, stream>>>(cursor, edges, x0, x1, nullptr, 1.0f);
    k_spmm<<<N_NODES, 256, 0, stream>>>(cursor, edges, x1, x2, x0, 2.0f);
    k_combine<<<157 * 8, 256, 0, stream>>>(x0, x1, x2, W, bias, out);
}